// Round 1
// 571.273 us; speedup vs baseline: 1.1074x; 1.1074x over previous
//
#include <hip/hip_runtime.h>
#include <hip/hip_bf16.h>
#include <stdint.h>

// Problem constants (MixtureOfLinear: B=4,S=2048,D=4096, E=8, top-2, rank 16)
#define T_TOKENS 8192
#define DIN      4096
#define DOUT     4096
#define NE       8
#define RANK     16
#define KEXT     128         // NE*RANK
#define KTOT     4224        // DIN + KEXT
#define NT       66          // KTOT / 64 K-tiles for k_main
#define SCALING  2.0f

typedef __attribute__((ext_vector_type(8))) short   short8;   // 8 bf16 in 4 VGPRs
typedef __attribute__((ext_vector_type(4))) float   float4v;

__device__ __forceinline__ unsigned short f2bf(float f) {
    union { float f; unsigned int u; } c; c.f = f;
    unsigned int u = c.u;
    u += 0x7FFFu + ((u >> 16) & 1u);          // round-to-nearest-even
    return (unsigned short)(u >> 16);
}

#define GLD_LDS(g, l) __builtin_amdgcn_global_load_lds( \
    (const __attribute__((address_space(1))) void*)(g), \
    (__attribute__((address_space(3))) void*)(l), 16, 0, 0)

// ---------------------------------------------------------------------------
// Kernel 1 (merged front-end, all parts independent):
//  blocks [0,2048):      x cast -> xa[:,0:4096] bf16 + fp32 router -> w8
//                        (one token per wave, 4 tokens per block)
//  blocks [2048,18432):  Wa[o,0:4096] = bf16(W_base)
//  blocks [18432,22528): Acat cast + Wa[:,4096:] = bf16(B) pack
// ---------------------------------------------------------------------------
__global__ __launch_bounds__(256) void k_front(const float* __restrict__ x,
                                               const float* __restrict__ Wr,
                                               const float* __restrict__ Wb,
                                               const float* __restrict__ A,
                                               const float* __restrict__ Bm,
                                               unsigned short* __restrict__ xa,
                                               unsigned short* __restrict__ Wa,
                                               unsigned short* __restrict__ Acat,
                                               float* __restrict__ w8) {
    __shared__ float lds_wr[8 * 1024];              // 8 experts x 1024 floats (32 KB)
    int b = blockIdx.x;
    int tid = threadIdx.x;

    if (b < 2048) {
        // ---- cast + router: token t handled by wave w ----
        int l = tid & 63, w = tid >> 6;
        int t = b * 4 + w;
        const float4* x4 = (const float4*)x;
        const float4* Wr4 = (const float4*)Wr;
        unsigned short* xarow = xa + (size_t)t * KTOT;

        float racc[NE];
#pragma unroll
        for (int e = 0; e < NE; e++) racc[e] = 0.f;

        for (int ci = 0; ci < 4; ci++) {            // 1024 floats per iter
            __syncthreads();
#pragma unroll
            for (int jj = 0; jj < 8; jj++) {        // stage Wr chunk (fp32)
                int f = jj * 256 + tid;             // float4 index 0..2047
                int e = f >> 8, col = f & 255;
                *(float4*)&lds_wr[f * 4] = Wr4[e * 1024 + ci * 256 + col];
            }
            __syncthreads();
            float4 xv[4];
#pragma unroll
            for (int j = 0; j < 4; j++)
                xv[j] = x4[(size_t)t * 1024 + ci * 256 + j * 64 + l];
#pragma unroll
            for (int j = 0; j < 4; j++) {
                ushort4 p;
                p.x = f2bf(xv[j].x); p.y = f2bf(xv[j].y);
                p.z = f2bf(xv[j].z); p.w = f2bf(xv[j].w);
                *(ushort4*)(xarow + (ci * 256 + j * 64 + l) * 4) = p;
            }
#pragma unroll
            for (int e = 0; e < NE; e++) {
#pragma unroll
                for (int j = 0; j < 4; j++) {
                    float4 wv = *(const float4*)&lds_wr[(e * 256 + j * 64 + l) * 4];
                    racc[e] += xv[j].x * wv.x + xv[j].y * wv.y + xv[j].z * wv.z + xv[j].w * wv.w;
                }
            }
        }
        // wave butterfly reduce (64 lanes)
#pragma unroll
        for (int e = 0; e < NE; e++) {
            float v = racc[e];
#pragma unroll
            for (int off = 32; off > 0; off >>= 1) v += __shfl_xor(v, off);
            racc[e] = v;
        }
        if (l == 0) {
            int e0 = 0;
#pragma unroll
            for (int e = 1; e < NE; e++) if (racc[e] > racc[e0]) e0 = e;
            int e1 = -1;
#pragma unroll
            for (int e = 0; e < NE; e++)
                if (e != e0 && (e1 < 0 || racc[e] > racc[e1])) e1 = e;
            float a1 = __expf(racc[e1] - racc[e0]);
            float inv = 1.0f / (1.0f + a1);
            float* wrow = w8 + t * NE;
#pragma unroll
            for (int e = 0; e < NE; e++)
                wrow[e] = (e == e0) ? inv * SCALING : ((e == e1) ? a1 * inv * SCALING : 0.f);
        }
    } else if (b < 18432) {
        // ---- W_base cast ----
        int idx = (b - 2048) * 256 + tid;           // 0 .. 4194303
        float4 v = ((const float4*)Wb)[idx];
        int o  = idx >> 10;
        int kc = idx & 1023;
        ushort4 p;
        p.x = f2bf(v.x); p.y = f2bf(v.y); p.z = f2bf(v.z); p.w = f2bf(v.w);
        *(ushort4*)(Wa + (size_t)o * KTOT + kc * 4) = p;
    } else {
        // ---- A cast + B pack ----
        int tid2 = (b - 18432) * 256 + tid;         // 0 .. 1048575
        if (tid2 < NE * RANK * DIN) {
            Acat[tid2] = f2bf(A[tid2]);
        } else {
            int j   = tid2 - NE * RANK * DIN;       // 0 .. 524287
            int o   = j >> 7;
            int rem = j & 127;                      // e*16 + r
            int e   = rem >> 4;
            int r   = rem & 15;
            Wa[(size_t)o * KTOT + DIN + rem] = f2bf(Bm[(size_t)e * (DOUT * RANK) + o * RANK + r]);
        }
    }
}

// ---------------------------------------------------------------------------
// k_h: h[t,er] = xa_bf16[t,:4096] · Acat[er,:], scaled by router weight,
// written into xa[t, 4096+er]. M=8192 N=128 K=4096. BM=32, BK=128, 32 iters.
// ---------------------------------------------------------------------------
__global__ __launch_bounds__(256) void k_h(unsigned short* __restrict__ xa,
                                           const unsigned short* __restrict__ Acat,
                                           const float* __restrict__ w8) {
    __shared__ unsigned short lds_x[32 * 128];      // 8 KB
    __shared__ unsigned short lds_a[128 * 128];     // 32 KB
    int m0  = blockIdx.x * 32;
    int tid = threadIdx.x;
    int l = tid & 63, w = tid >> 6;
    int quad = l >> 4, lr = l & 15;

    float4v acc[2][2] = {};                         // [mi][ni]

    for (int k0 = 0; k0 < DIN; k0 += 128) {
        __syncthreads();
#pragma unroll
        for (int it = 0; it < 2; it++) {            // x tile: 512 chunks
            int c = it * 256 + tid;
            int row = c >> 4, s = c & 15;
            int kc = s ^ (row & 15);
            GLD_LDS(xa + (size_t)(m0 + row) * KTOT + k0 + kc * 8, lds_x + c * 8);
        }
#pragma unroll
        for (int it = 0; it < 8; it++) {            // A tile: 2048 chunks
            int c = it * 256 + tid;
            int row = c >> 4, s = c & 15;
            int kc = s ^ (row & 15);
            GLD_LDS(Acat + (size_t)row * DIN + k0 + kc * 8, lds_a + c * 8);
        }
        __syncthreads();
#pragma unroll
        for (int kk = 0; kk < 4; kk++) {
            int kc = kk * 4 + quad;
            short8 a[2], bfr[2];
#pragma unroll
            for (int mi = 0; mi < 2; mi++) {
                int row = mi * 16 + lr;
                a[mi] = *(const short8*)&lds_x[row * 128 + ((kc ^ lr) * 8)];
            }
#pragma unroll
            for (int ni = 0; ni < 2; ni++) {
                int row = w * 32 + ni * 16 + lr;
                bfr[ni] = *(const short8*)&lds_a[row * 128 + ((kc ^ lr) * 8)];
            }
#pragma unroll
            for (int mi = 0; mi < 2; mi++)
#pragma unroll
                for (int ni = 0; ni < 2; ni++)
                    acc[mi][ni] = __builtin_amdgcn_mfma_f32_16x16x32_bf16(a[mi], bfr[ni], acc[mi][ni], 0, 0, 0);
        }
    }

#pragma unroll
    for (int mi = 0; mi < 2; mi++)
#pragma unroll
        for (int ni = 0; ni < 2; ni++) {
            int col = w * 32 + ni * 16 + lr;        // er index 0..127
            int e = col >> 4;
#pragma unroll
            for (int i = 0; i < 4; i++) {
                int t = m0 + mi * 16 + quad * 4 + i;
                float v = acc[mi][ni][i] * w8[t * NE + e];
                xa[(size_t)t * KTOT + DIN + col] = f2bf(v);
            }
        }
}

// ---------------------------------------------------------------------------
// Main GEMM: out[t,o] = b_base[o] + xa[t,:]·Wa[o,:], K=4224 = 66 tiles of 64.
// 256x256 tile, 8 waves (2M x 4N), 4 phases per K-tile (= 8-phase/2-tiles
// template, T1+T2+T3/T4+T5):
//   phase: {ds_read frags (4 or 8 b128, XOR-swizzled) | stage 1 region via
//           2x global_load_lds} -> s_barrier -> lgkmcnt(0) -> setprio(1),
//           16 MFMA, setprio(0) -> s_barrier
// Counted vmcnt(4) once per K-tile (never 0): staged loads stay in flight
// across barriers.  LDS 128 KiB: A[2buf][2kh][16KB] + B likewise.
// Swizzle (both-sides): LDS chunk s in a 16-row/1KB block holds global
// (row = s>>2 & 15, kchunk = (s&3) ^ ((row>>1)&3)); frag read uses
// chunk = lr*4 + (quad ^ ((lr>>1)&3))  -> all 8 bank-groups distinct per
// 8-lane group (conflict-free ds_read_b128).
// ---------------------------------------------------------------------------
#define LOADA(dst, basep, mlo) { \
    _Pragma("unroll") for (int i_ = 0; i_ < 4; i_++) \
        dst[i_] = *(const short8*)((basep) + aoff + ((mlo) + i_) * 1024); }
#define LOADB(dst, basep) { \
    _Pragma("unroll") for (int i_ = 0; i_ < 4; i_++) \
        dst[i_] = *(const short8*)((basep) + boff + i_ * 1024); }
#define MFMA44(mlo) { \
    __builtin_amdgcn_s_setprio(1); \
    _Pragma("unroll") for (int i_ = 0; i_ < 4; i_++) \
    _Pragma("unroll") for (int j_ = 0; j_ < 4; j_++) \
        acc[(mlo) + i_][j_] = __builtin_amdgcn_mfma_f32_16x16x32_bf16(af[i_], bf[j_], acc[(mlo) + i_][j_], 0, 0, 0); \
    __builtin_amdgcn_s_setprio(0); }
#define STAGE(srcP, regbase, ts, kh, tb) do { \
    const unsigned short* s_ = (srcP) + (size_t)((ts) * 64 + (kh) * 32); \
    char* d_ = smem + (regbase) + (tb) * 32768 + (kh) * 16384 + tid16; \
    GLD_LDS(s_, d_); \
    GLD_LDS(s_ + (size_t)128 * KTOT, d_ + 8192); \
} while (0)
#define BAR() __builtin_amdgcn_s_barrier()
#define LGKM0() do { asm volatile("s_waitcnt lgkmcnt(0)" ::: "memory"); \
                     __builtin_amdgcn_sched_barrier(0); } while (0)

__global__ __launch_bounds__(512, 2) void k_main(const unsigned short* __restrict__ xa,
                                                 const unsigned short* __restrict__ Wa,
                                                 const float* __restrict__ bias,
                                                 float* __restrict__ out) {
    extern __shared__ char smem[];                  // 131072 B dynamic
    int tid = threadIdx.x;
    int l = tid & 63, w = tid >> 6;
    int lr = l & 15, quad = l >> 4;
    int wm = w >> 2, wn = w & 3;

    // XCD-bijective swizzle: 512 wgs = 8 XCD x 64; each XCD gets a
    // contiguous 64-wg chunk (2 bn columns x 32 bm) for L2 reuse.
    int bid = blockIdx.x;
    int wg  = (bid & 7) * 64 + (bid >> 3);
    int bm  = wg & 31, bn = wg >> 5;

    // ds_read side of the swizzle
    int laneoff = (lr * 4 + (quad ^ ((lr >> 1) & 3))) * 16;   // bytes in 1KB block
    int aoff = wm * 8192 + laneoff;                 // A: 16-row block = wm*8+mi
    int boff = wn * 4096 + laneoff;                 // B: 16-row block = wn*4+ni

    // stage side (inverse swizzle on the GLOBAL source; LDS dest linear):
    // LDS chunk s = it*512 + tid -> row = (s>>6)*16 + ((s>>2)&15),
    //                               kchunk = (s&3) ^ (((s>>2)&15 >>1)&3)
    int srow  = w * 16 + ((tid >> 2) & 15);         // it=0 rows 0..127 (+128 for it=1)
    int skq   = (tid & 3) ^ ((tid >> 3) & 3);
    int tid16 = tid * 16;
    const unsigned short* srcA = xa + (size_t)(bm * 256 + srow) * KTOT + skq * 8;
    const unsigned short* srcB = Wa + (size_t)(bn * 256 + srow) * KTOT + skq * 8;

    float4v acc[8][4] = {};                         // [mi 0..7][ni 0..3]
    short8 af[4], bf[4];

    // ---- prologue: tile0 (all 4 regions) + tile1 k-half0 = 12 loads/thread
    STAGE(srcA, 0,     0, 0, 0);
    STAGE(srcB, 65536, 0, 0, 0);
    STAGE(srcA, 0,     0, 1, 0);
    STAGE(srcB, 65536, 0, 1, 0);
    STAGE(srcA, 0,     1, 0, 1);
    STAGE(srcB, 65536, 1, 0, 1);
    asm volatile("s_waitcnt vmcnt(4)" ::: "memory");  // tile0 landed; t1k0 in flight
    BAR();

    for (int t = 0; t < NT; ++t) {
        int buf  = t & 1, nbuf = buf ^ 1;
        int ts1  = (t + 1 < NT) ? t + 1 : NT - 1;   // clamp: dup stage, slot dead
        int ts2  = (t + 2 < NT) ? t + 2 : NT - 1;
        const char* pa = smem + buf * 32768;          // A kh0 (kh1 at +16384)
        const char* pb = smem + 65536 + buf * 32768;  // B kh0

        // phase 1: A mi0-3 kh0 + B kh0 (8 reads); stage A(t+1,k1)->nbuf
        LOADA(af, pa, 0);
        LOADB(bf, pb);
        STAGE(srcA, 0, ts1, 1, nbuf);
        BAR(); LGKM0();
        MFMA44(0);
        BAR();

        // phase 2: A mi4-7 kh0 (4 reads, bf reused); stage B(t+1,k1)->nbuf
        LOADA(af, pa, 4);
        STAGE(srcB, 65536, ts1, 1, nbuf);
        BAR(); LGKM0();
        MFMA44(4);
        BAR();

        // phase 3: A mi0-3 kh1 + B kh1 (8 reads); stage A(t+2,k0)->buf
        //          (A(t,k0) died after phase-2 end barrier)
        LOADA(af, pa + 16384, 0);
        LOADB(bf, pb + 16384);
        STAGE(srcA, 0, ts2, 0, buf);
        BAR(); LGKM0();
        MFMA44(0);
        BAR();

        // phase 4: A mi4-7 kh1; stage B(t+2,k0)->buf; ONE counted wait:
        // 12 outstanding -> vmcnt(4) drains tile t+1 fully, leaves t+2 k0.
        LOADA(af, pa + 16384, 4);
        STAGE(srcB, 65536, ts2, 0, buf);
        asm volatile("s_waitcnt vmcnt(4)" ::: "memory");
        BAR(); LGKM0();
        MFMA44(4);
        BAR();
    }

    // ---- epilogue: C = acc + bias
    int trow0 = bm * 256 + wm * 128;
    int ocol0 = bn * 256 + wn * 64;
#pragma unroll
    for (int ni = 0; ni < 4; ni++) {
        int o = ocol0 + ni * 16 + lr;
        float bb = bias[o];
#pragma unroll
        for (int mi = 0; mi < 8; mi++) {
#pragma unroll
            for (int i = 0; i < 4; i++) {
                int trow = trow0 + mi * 16 + quad * 4 + i;
                out[(size_t)trow * DOUT + o] = acc[mi][ni][i] + bb;
            }
        }
    }
}

// ---------------------------------------------------------------------------
extern "C" void kernel_launch(void* const* d_in, const int* in_sizes, int n_in,
                              void* d_out, int out_size, void* d_ws, size_t ws_size,
                              hipStream_t stream) {
    const float* x  = (const float*)d_in[0];   // [4,2048,4096]
    const float* Wb = (const float*)d_in[1];   // [4096,4096]
    const float* bb = (const float*)d_in[2];   // [4096]
    const float* Wr = (const float*)d_in[3];   // [8,4096]
    const float* A  = (const float*)d_in[4];   // [8,16,4096]
    const float* Bm = (const float*)d_in[5];   // [8,4096,16]
    float* out = (float*)d_out;

    char* ws = (char*)d_ws;
    unsigned short* xa   = (unsigned short*)(ws);                       // 8192*4224*2 = 69,206,016 B
    unsigned short* Wa   = (unsigned short*)(ws + 69206016);            // 4096*4224*2 = 34,603,008 B
    unsigned short* Acat = (unsigned short*)(ws + 69206016 + 34603008); // 128*4096*2  =  1,048,576 B
    float*          w8   = (float*)(ws + 69206016 + 34603008 + 1048576);// 8192*8*4    =    262,144 B
    // total: 105,119,744 B

    static bool attr_done = false;
    if (!attr_done) {
        hipFuncSetAttribute((const void*)k_main,
                            hipFuncAttributeMaxDynamicSharedMemorySize, 131072);
        attr_done = true;
    }

    k_front<<<dim3(22528), dim3(256), 0, stream>>>(x, Wr, Wb, A, Bm, xa, Wa, Acat, w8);
    k_h    <<<dim3(256),   dim3(256), 0, stream>>>(xa, Acat, w8);
    k_main <<<dim3(512),   dim3(512), 131072, stream>>>(xa, Wa, bb, out);
}